// Round 2
// baseline (1495.382 us; speedup 1.0000x reference)
//
#include <hip/hip_runtime.h>

typedef __bf16 bf16;
typedef __bf16 bf16x2 __attribute__((ext_vector_type(2)));
typedef __bf16 bf16x4 __attribute__((ext_vector_type(4)));
typedef __bf16 bf16x8 __attribute__((ext_vector_type(8)));
typedef float f32x4 __attribute__((ext_vector_type(4)));

#define NN 50000
#define NE 800000
#define EMB 128
#define EDGE_F 16
#define NLAYER 5

// ---------------------------------------------------------------------------
// Weight swizzle + fp32->bf16 convert: row-major [K][N] -> [(k/32)][n][k%32]
// so an MFMA B-fragment (n = lane&15, k = (lane>>4)*8 + j) is one contiguous
// 16B load per lane. Also builds WeT[l][c][f] = We[l][f][c] (kept fp32).
// ---------------------------------------------------------------------------
__global__ __launch_bounds__(256) void swz_kernel(
    const float* __restrict__ Wx, const float* __restrict__ W1,
    const float* __restrict__ W2, const float* __restrict__ We,
    bf16* __restrict__ wx_s, bf16* __restrict__ w1_s,
    bf16* __restrict__ w2_s, float* __restrict__ weT)
{
    int t = blockIdx.x * 256 + threadIdx.x;
    if (t < 16384) {                                   // Wx: K=128,N=128
        int k = t >> 7, n = t & 127;
        wx_s[(((k >> 5) << 7) + n) * 32 + (k & 31)] = (bf16)Wx[t];
    } else if (t < 16384 + 163840) {                   // W1: 5 x (K=128,N=256)
        int u = t - 16384;
        int l = u / 32768, r = u % 32768;
        int k = r >> 8, n = r & 255;
        w1_s[l * 32768 + (((k >> 5) << 8) + n) * 32 + (k & 31)] = (bf16)W1[u];
    } else if (t < 16384 + 327680) {                   // W2: 5 x (K=256,N=128)
        int u = t - (16384 + 163840);
        int l = u / 32768, r = u % 32768;
        int k = r >> 7, n = r & 127;
        w2_s[l * 32768 + (((k >> 5) << 7) + n) * 32 + (k & 31)] = (bf16)W2[u];
    } else if (t < 16384 + 327680 + 10240) {           // WeT: 5 x [128][16] fp32
        int u = t - (16384 + 327680);
        int l = u >> 11, r = u & 2047;
        int c = r >> 4, f = r & 15;
        weT[u] = We[l * 2048 + f * 128 + c];
    }
}

// ---------------------------------------------------------------------------
// CSR build
// ---------------------------------------------------------------------------
__global__ void count_kernel(const int* __restrict__ dst, int* __restrict__ deg, int nE)
{
    int e = blockIdx.x * 256 + threadIdx.x;
    if (e < nE) atomicAdd(&deg[dst[e]], 1);
}

__global__ __launch_bounds__(256) void scan_kernel(
    const int* __restrict__ deg, int* __restrict__ rowstart,
    int* __restrict__ cursor, int n)
{
    __shared__ int tot[256];
    __shared__ int pre[257];
    int tid = threadIdx.x;
    int C = (n + 255) >> 8;
    int base = tid * C;
    int s = 0;
    for (int j = 0; j < C; ++j) { int idx = base + j; if (idx < n) s += deg[idx]; }
    tot[tid] = s;
    __syncthreads();
    if (tid == 0) {
        int r = 0;
        for (int t = 0; t < 256; ++t) { pre[t] = r; r += tot[t]; }
        pre[256] = r;
    }
    __syncthreads();
    int run = pre[tid];
    for (int j = 0; j < C; ++j) {
        int idx = base + j;
        if (idx < n) { rowstart[idx] = run; cursor[idx] = run; run += deg[idx]; }
    }
    if (tid == 0) rowstart[n] = pre[256];
}

__global__ void fill_kernel(const int* __restrict__ src, const int* __restrict__ dst,
                            int* __restrict__ cursor, int2* __restrict__ csr, int nE)
{
    int e = blockIdx.x * 256 + threadIdx.x;
    if (e < nE) {
        int d = dst[e];
        int pos = atomicAdd(&cursor[d], 1);
        csr[pos] = make_int2(src[e], e);
    }
}

// ---------------------------------------------------------------------------
// ea_agg[i][f] = sum over in-edges e of edge_attr[e][f]  (layer-independent)
// 16 lanes per node. edge_attr is fp32.
// ---------------------------------------------------------------------------
__global__ __launch_bounds__(256) void ea_gather_kernel(
    const float* __restrict__ edge_attr, const int* __restrict__ rowstart,
    const int2* __restrict__ csr, float* __restrict__ ea_agg, int n)
{
    int node = blockIdx.x * 16 + (threadIdx.x >> 4);
    int f = threadIdx.x & 15;
    if (node >= n) return;
    int rs = rowstart[node], re = rowstart[node + 1];
    float a = 0.f;
    for (int j = rs; j < re; ++j) {
        int e = csr[j].y;
        a += edge_attr[(size_t)e * EDGE_F + f];
    }
    ea_agg[node * EDGE_F + f] = a;
}

// ---------------------------------------------------------------------------
// agg[i] = sum_{e:dst=i} h[src_e] + h[i] + ea_agg[i]@We[l] + (deg+1)*be[l]
// One wave per node; lane handles channels 2*lane, 2*lane+1. h is bf16,
// fp32 accumulate, bf16 output (MFMA A operand for GEMM1).
// ---------------------------------------------------------------------------
__global__ __launch_bounds__(256) void agg_kernel(
    const bf16* __restrict__ h, const int* __restrict__ rowstart,
    const int2* __restrict__ csr, const float* __restrict__ ea_agg,
    const float* __restrict__ weT_l, const float* __restrict__ be_l,
    bf16* __restrict__ agg, int n)
{
    int lane = threadIdx.x & 63;
    int node = blockIdx.x * 4 + (threadIdx.x >> 6);
    if (node >= n) return;
    int rs = rowstart[node], re = rowstart[node + 1];
    int c0 = lane * 2;
    float ax = 0.f, ay = 0.f;
    int j = rs;
    for (; j + 4 <= re; j += 4) {   // 4 outstanding gathers to hide L2/L3 latency
        int s0 = csr[j].x, s1 = csr[j + 1].x, s2 = csr[j + 2].x, s3 = csr[j + 3].x;
        bf16x2 h0 = *(const bf16x2*)(h + (size_t)s0 * EMB + c0);
        bf16x2 h1 = *(const bf16x2*)(h + (size_t)s1 * EMB + c0);
        bf16x2 h2v = *(const bf16x2*)(h + (size_t)s2 * EMB + c0);
        bf16x2 h3 = *(const bf16x2*)(h + (size_t)s3 * EMB + c0);
        ax += (float)h0.x + (float)h1.x + (float)h2v.x + (float)h3.x;
        ay += (float)h0.y + (float)h1.y + (float)h2v.y + (float)h3.y;
    }
    for (; j < re; ++j) {
        int s = csr[j].x;
        bf16x2 hv = *(const bf16x2*)(h + (size_t)s * EMB + c0);
        ax += (float)hv.x; ay += (float)hv.y;
    }
    {   // self loop: + h[i]
        bf16x2 hv = *(const bf16x2*)(h + (size_t)node * EMB + c0);
        ax += (float)hv.x; ay += (float)hv.y;
    }
    {   // + ea_agg[i] @ We[l]   (WeT fp32 layout: [c][16f] contiguous)
        const float* ea = ea_agg + node * EDGE_F;
        const float* w0 = weT_l + (size_t)c0 * 16;
        const float* w1 = weT_l + (size_t)(c0 + 1) * 16;
#pragma unroll
        for (int f = 0; f < 16; ++f) {
            float ef = ea[f];
            ax += ef * w0[f];
            ay += ef * w1[f];
        }
    }
    {   // + (deg+1) * be[l]
        float dp1 = (float)(re - rs + 1);
        ax += dp1 * be_l[c0];
        ay += dp1 * be_l[c0 + 1];
    }
    bf16x2 o; o.x = (bf16)ax; o.y = (bf16)ay;
    *(bf16x2*)(agg + (size_t)node * EMB + c0) = o;
}

// ---------------------------------------------------------------------------
// GEMM: C[M,N] = op(A[M,K] @ Bswz + bias). One wave computes a 16-row x N
// strip. A-fragments (bf16, or fp32 converted in-flight) and pre-swizzled
// bf16 B-fragments are direct 16B global loads (no LDS). Output bf16.
// Optional fused per-column fp32 sum/sumsq stats (for BatchNorm).
// M = 50000 is divisible by 16 -> no row guards inside a strip.
// ---------------------------------------------------------------------------
template <int K, int N, bool RELU, bool AFP32, bool STATS>
__global__ __launch_bounds__(256) void gemm_kernel(
    const void* __restrict__ Ap, const bf16* __restrict__ Bswz,
    const float* __restrict__ bias, bf16* __restrict__ outp,
    float* __restrict__ sums, float* __restrict__ sumsq, int M)
{
    const int lane = threadIdx.x & 63;
    const int wave = threadIdx.x >> 6;
    const int m0 = (blockIdx.x * 4 + wave) * 16;
    if (m0 >= M) return;
    const int m = lane & 15, q = lane >> 4;
    constexpr int NF = N / 16, KB = K / 32;

    f32x4 acc[NF];
#pragma unroll
    for (int f = 0; f < NF; ++f) acc[f] = 0.f;

#pragma unroll
    for (int kb = 0; kb < KB; ++kb) {
        bf16x8 a;
        if constexpr (AFP32) {
            const float* ar = (const float*)Ap + (size_t)(m0 + m) * K + kb * 32 + q * 8;
            f32x4 v0 = *(const f32x4*)ar;
            f32x4 v1 = *(const f32x4*)(ar + 4);
#pragma unroll
            for (int j = 0; j < 4; ++j) { a[j] = (bf16)v0[j]; a[4 + j] = (bf16)v1[j]; }
        } else {
            const bf16* ar = (const bf16*)Ap + (size_t)(m0 + m) * K + kb * 32 + q * 8;
            a = *(const bf16x8*)ar;
        }
#pragma unroll
        for (int f = 0; f < NF; ++f) {
            bf16x8 b = *(const bf16x8*)(Bswz + ((size_t)(kb * N + f * 16 + m)) * 32 + q * 8);
            acc[f] = __builtin_amdgcn_mfma_f32_16x16x32_bf16(a, b, acc[f], 0, 0, 0);
        }
    }

#pragma unroll
    for (int f = 0; f < NF; ++f) {
        const int col = f * 16 + m;
        float bv = bias[col];
        float s1 = 0.f, s2 = 0.f;
#pragma unroll
        for (int r = 0; r < 4; ++r) {
            float v = acc[f][r] + bv;
            if (RELU) v = fmaxf(v, 0.f);
            int row = m0 + q * 4 + r;
            outp[(size_t)row * N + col] = (bf16)v;
            if constexpr (STATS) { s1 += v; s2 += v * v; }
        }
        if constexpr (STATS) {
            s1 += __shfl_xor(s1, 16); s1 += __shfl_xor(s1, 32);
            s2 += __shfl_xor(s2, 16); s2 += __shfl_xor(s2, 32);
            if (q == 0) { atomicAdd(&sums[col], s1); atomicAdd(&sumsq[col], s2); }
        }
    }
}

// ---------------------------------------------------------------------------
// BatchNorm normalize (+optional relu), bf16 in -> bf16 (intermediate h) or
// fp32 (final d_out). scale/shift recomputed per block from sums/sumsq.
// ---------------------------------------------------------------------------
__global__ __launch_bounds__(256) void norm_kernel(
    const bf16* __restrict__ h2, const float* __restrict__ sums,
    const float* __restrict__ sumsq, const float* __restrict__ gamma,
    const float* __restrict__ beta, void* __restrict__ outp, int n,
    int relu, int out_fp32)
{
    __shared__ float sc[EMB], sh[EMB];
    int tid = threadIdx.x;
    if (tid < EMB) {
        float inv_n = 1.0f / (float)n;
        float mean = sums[tid] * inv_n;
        float var = sumsq[tid] * inv_n - mean * mean;
        float s = gamma[tid] * rsqrtf(var + 1e-5f);
        sc[tid] = s;
        sh[tid] = beta[tid] - mean * s;
    }
    __syncthreads();
    int total4 = n * (EMB / 4);
    int stride = gridDim.x * blockDim.x;
    for (int i = blockIdx.x * blockDim.x + tid; i < total4; i += stride) {
        bf16x4 hv = ((const bf16x4*)h2)[i];
        int c0 = (i * 4) & (EMB - 1);
        float v0 = (float)hv.x * sc[c0] + sh[c0];
        float v1 = (float)hv.y * sc[c0 + 1] + sh[c0 + 1];
        float v2 = (float)hv.z * sc[c0 + 2] + sh[c0 + 2];
        float v3 = (float)hv.w * sc[c0 + 3] + sh[c0 + 3];
        if (relu) {
            v0 = fmaxf(v0, 0.f); v1 = fmaxf(v1, 0.f);
            v2 = fmaxf(v2, 0.f); v3 = fmaxf(v3, 0.f);
        }
        if (out_fp32) {
            f32x4 o; o.x = v0; o.y = v1; o.z = v2; o.w = v3;
            ((f32x4*)outp)[i] = o;
        } else {
            bf16x4 o;
            o.x = (bf16)v0; o.y = (bf16)v1; o.z = (bf16)v2; o.w = (bf16)v3;
            ((bf16x4*)outp)[i] = o;
        }
    }
}

// ---------------------------------------------------------------------------
extern "C" void kernel_launch(void* const* d_in, const int* in_sizes, int n_in,
                              void* d_out, int out_size, void* d_ws, size_t ws_size,
                              hipStream_t stream)
{
    const float* x         = (const float*)d_in[0];
    const float* edge_attr = (const float*)d_in[1];
    const int*   eidx      = (const int*)d_in[2];
    const float* Wx        = (const float*)d_in[3];
    const float* bx        = (const float*)d_in[4];
    const float* We        = (const float*)d_in[5];
    const float* be        = (const float*)d_in[6];
    const float* W1        = (const float*)d_in[7];
    const float* b1        = (const float*)d_in[8];
    const float* W2        = (const float*)d_in[9];
    const float* b2        = (const float*)d_in[10];
    const float* gamma     = (const float*)d_in[11];
    const float* beta      = (const float*)d_in[12];

    // ---- workspace layout (poisoned 0xAA before every call) ----
    size_t off = 0;
    char* base = (char*)d_ws;
    auto alloc = [&](size_t bytes) -> void* {
        void* p = base + off;
        off += (bytes + 255) & ~(size_t)255;
        return p;
    };
    int*   deg      = (int*)alloc(NN * 4);
    float* sums     = (float*)alloc(NLAYER * EMB * 4);
    float* sumsq    = (float*)alloc(NLAYER * EMB * 4);
    size_t zero_bytes = off;                       // deg+sums+sumsq zeroed
    int*   rowstart = (int*)alloc((NN + 1) * 4);
    int*   cursor   = (int*)alloc(NN * 4);
    int2*  csr      = (int2*)alloc((size_t)NE * 8);
    float* ea_agg   = (float*)alloc((size_t)NN * EDGE_F * 4);
    bf16*  h        = (bf16*)alloc((size_t)NN * EMB * 2);
    bf16*  aggb     = (bf16*)alloc((size_t)NN * EMB * 2);
    bf16*  t1       = (bf16*)alloc((size_t)NN * 2 * EMB * 2);
    bf16*  h2b      = (bf16*)alloc((size_t)NN * EMB * 2);
    bf16*  wx_s     = (bf16*)alloc(16384 * 2);
    bf16*  w1_s     = (bf16*)alloc(163840 * 2);
    bf16*  w2_s     = (bf16*)alloc(163840 * 2);
    float* weT      = (float*)alloc(10240 * 4);
    (void)ws_size; (void)in_sizes; (void)n_in; (void)out_size;

    const int* src = eidx;
    const int* dst = eidx + NE;

    hipMemsetAsync(d_ws, 0, zero_bytes, stream);

    swz_kernel<<<1384, 256, 0, stream>>>(Wx, W1, W2, We, wx_s, w1_s, w2_s, weT);
    count_kernel<<<NE / 256, 256, 0, stream>>>(dst, deg, NE);
    scan_kernel<<<1, 256, 0, stream>>>(deg, rowstart, cursor, NN);
    fill_kernel<<<NE / 256, 256, 0, stream>>>(src, dst, cursor, csr, NE);
    ea_gather_kernel<<<NN / 16, 256, 0, stream>>>(edge_attr, rowstart, csr, ea_agg, NN);

    // h = x @ Wx + bx  (x is fp32, converted in-kernel)
    const int gemm_blocks = (NN / 16 + 3) / 4;   // 782
    gemm_kernel<128, 128, false, true, false><<<gemm_blocks, 256, 0, stream>>>(
        x, wx_s, bx, h, nullptr, nullptr, NN);

    for (int l = 0; l < NLAYER; ++l) {
        agg_kernel<<<NN / 4, 256, 0, stream>>>(
            h, rowstart, csr, ea_agg, weT + l * 2048, be + l * EMB, aggb, NN);
        gemm_kernel<128, 256, true, false, false><<<gemm_blocks, 256, 0, stream>>>(
            aggb, w1_s + l * 32768, b1 + l * 2 * EMB, t1, nullptr, nullptr, NN);
        gemm_kernel<256, 128, false, false, true><<<gemm_blocks, 256, 0, stream>>>(
            t1, w2_s + l * 32768, b2 + l * EMB, h2b, sums + l * EMB, sumsq + l * EMB, NN);
        norm_kernel<<<1024, 256, 0, stream>>>(
            h2b, sums + l * EMB, sumsq + l * EMB, gamma + l * EMB, beta + l * EMB,
            (l == NLAYER - 1) ? d_out : (void*)h, NN,
            (l < NLAYER - 1) ? 1 : 0, (l == NLAYER - 1) ? 1 : 0);
    }
}

// Round 3
// 1030.311 us; speedup vs baseline: 1.4514x; 1.4514x over previous
//
#include <hip/hip_runtime.h>

typedef __bf16 bf16;
typedef __bf16 bf16x2 __attribute__((ext_vector_type(2)));
typedef __bf16 bf16x4 __attribute__((ext_vector_type(4)));
typedef __bf16 bf16x8 __attribute__((ext_vector_type(8)));
typedef float f32x4 __attribute__((ext_vector_type(4)));

#define NN 50000
#define NE 800000
#define EMB 128
#define EDGE_F 16
#define NLAYER 5
#define SCAN_BLOCKS 196   // ceil(50000/256)

// ---------------------------------------------------------------------------
// Weight swizzle + fp32->bf16 convert: row-major [K][N] -> [(k/32)][n][k%32]
// so an MFMA B-fragment (n = lane&15, k = (lane>>4)*8 + j) is one contiguous
// 16B load per lane. Also builds WeT[l][c][f] = We[l][f][c] (kept fp32).
// ---------------------------------------------------------------------------
__global__ __launch_bounds__(256) void swz_kernel(
    const float* __restrict__ Wx, const float* __restrict__ W1,
    const float* __restrict__ W2, const float* __restrict__ We,
    bf16* __restrict__ wx_s, bf16* __restrict__ w1_s,
    bf16* __restrict__ w2_s, float* __restrict__ weT)
{
    int t = blockIdx.x * 256 + threadIdx.x;
    if (t < 16384) {                                   // Wx: K=128,N=128
        int k = t >> 7, n = t & 127;
        wx_s[(((k >> 5) << 7) + n) * 32 + (k & 31)] = (bf16)Wx[t];
    } else if (t < 16384 + 163840) {                   // W1: 5 x (K=128,N=256)
        int u = t - 16384;
        int l = u / 32768, r = u % 32768;
        int k = r >> 8, n = r & 255;
        w1_s[l * 32768 + (((k >> 5) << 8) + n) * 32 + (k & 31)] = (bf16)W1[u];
    } else if (t < 16384 + 327680) {                   // W2: 5 x (K=256,N=128)
        int u = t - (16384 + 163840);
        int l = u / 32768, r = u % 32768;
        int k = r >> 7, n = r & 127;
        w2_s[l * 32768 + (((k >> 5) << 7) + n) * 32 + (k & 31)] = (bf16)W2[u];
    } else if (t < 16384 + 327680 + 10240) {           // WeT: 5 x [128][16] fp32
        int u = t - (16384 + 327680);
        int l = u >> 11, r = u & 2047;
        int c = r >> 4, f = r & 15;
        weT[u] = We[l * 2048 + f * 128 + c];
    }
}

// ---------------------------------------------------------------------------
// CSR build: count -> hierarchical scan (3 small kernels) -> fill
// ---------------------------------------------------------------------------
__global__ void count_kernel(const int* __restrict__ dst, int* __restrict__ deg, int nE)
{
    int e = blockIdx.x * 256 + threadIdx.x;
    if (e < nE) atomicAdd(&deg[dst[e]], 1);
}

__global__ __launch_bounds__(256) void deg_bsum_kernel(
    const int* __restrict__ deg, int* __restrict__ bsum, int n)
{
    __shared__ int red[256];
    int i = blockIdx.x * 256 + threadIdx.x;
    red[threadIdx.x] = (i < n) ? deg[i] : 0;
    __syncthreads();
    for (int s = 128; s > 0; s >>= 1) {
        if (threadIdx.x < s) red[threadIdx.x] += red[threadIdx.x + s];
        __syncthreads();
    }
    if (threadIdx.x == 0) bsum[blockIdx.x] = red[0];
}

__global__ __launch_bounds__(256) void bsum_scan_kernel(
    const int* __restrict__ bsum, int* __restrict__ boff,
    int* __restrict__ rowstart, int nb, int n)
{
    __shared__ int v[256];
    int t = threadIdx.x;
    v[t] = (t < nb) ? bsum[t] : 0;
    __syncthreads();
    if (t == 0) {
        int r = 0;
        for (int i = 0; i < nb; ++i) { int x = v[i]; v[i] = r; r += x; }
        rowstart[n] = r;
    }
    __syncthreads();
    if (t < nb) boff[t] = v[t];
}

__global__ __launch_bounds__(256) void chunk_scan_kernel(
    const int* __restrict__ deg, const int* __restrict__ boff,
    int* __restrict__ rowstart, int* __restrict__ cursor, int n)
{
    __shared__ int v[256];
    int t = threadIdx.x;
    int i = blockIdx.x * 256 + t;
    int x = (i < n) ? deg[i] : 0;
    v[t] = x;
    __syncthreads();
    // Hillis-Steele inclusive scan
    for (int s = 1; s < 256; s <<= 1) {
        int add = (t >= s) ? v[t - s] : 0;
        __syncthreads();
        v[t] += add;
        __syncthreads();
    }
    int ex = v[t] - x + boff[blockIdx.x];
    if (i < n) { rowstart[i] = ex; cursor[i] = ex; }
}

__global__ void fill_kernel(const int* __restrict__ src, const int* __restrict__ dst,
                            int* __restrict__ cursor, int* __restrict__ csr_src,
                            int* __restrict__ csr_e, int nE)
{
    int e = blockIdx.x * 256 + threadIdx.x;
    if (e < nE) {
        int d = dst[e];
        int pos = atomicAdd(&cursor[d], 1);
        csr_src[pos] = src[e];
        csr_e[pos] = e;
    }
}

// ---------------------------------------------------------------------------
// ea_agg[i][f] = sum over in-edges e of edge_attr[e][f]  (layer-independent)
// 16 lanes per node. edge_attr is fp32.
// ---------------------------------------------------------------------------
__global__ __launch_bounds__(256) void ea_gather_kernel(
    const float* __restrict__ edge_attr, const int* __restrict__ rowstart,
    const int* __restrict__ csr_e, float* __restrict__ ea_agg, int n)
{
    int node = blockIdx.x * 16 + (threadIdx.x >> 4);
    int f = threadIdx.x & 15;
    if (node >= n) return;
    int rs = rowstart[node], re = rowstart[node + 1];
    float a = 0.f;
    for (int j = rs; j < re; ++j) {
        int e = csr_e[j];
        a += edge_attr[(size_t)e * EDGE_F + f];
    }
    ea_agg[node * EDGE_F + f] = a;
}

// ---------------------------------------------------------------------------
// agg[i] = sum_{e:dst=i} h[src_e] + h[i] + ea_agg[i]@We[l] + (deg+1)*be[l]
// One wave per node; lane handles channels 2*lane, 2*lane+1. h is bf16,
// fp32 accumulate, bf16 output (MFMA A operand for GEMM1).
// 8 outstanding gathers per iteration to hide L2/L3 latency.
// ---------------------------------------------------------------------------
__global__ __launch_bounds__(256) void agg_kernel(
    const bf16* __restrict__ h, const int* __restrict__ rowstart,
    const int* __restrict__ csr_src, const float* __restrict__ ea_agg,
    const float* __restrict__ weT_l, const float* __restrict__ be_l,
    bf16* __restrict__ agg, int n)
{
    int lane = threadIdx.x & 63;
    int node = blockIdx.x * 4 + (threadIdx.x >> 6);
    if (node >= n) return;
    int rs = rowstart[node], re = rowstart[node + 1];
    int c0 = lane * 2;
    float ax = 0.f, ay = 0.f;
    // self loop issued first (independent load)
    bf16x2 hself = *(const bf16x2*)(h + (size_t)node * EMB + c0);
    int j = rs;
    for (; j + 8 <= re; j += 8) {
        int s0 = csr_src[j], s1 = csr_src[j + 1], s2 = csr_src[j + 2], s3 = csr_src[j + 3];
        int s4 = csr_src[j + 4], s5 = csr_src[j + 5], s6 = csr_src[j + 6], s7 = csr_src[j + 7];
        bf16x2 h0 = *(const bf16x2*)(h + (size_t)s0 * EMB + c0);
        bf16x2 h1 = *(const bf16x2*)(h + (size_t)s1 * EMB + c0);
        bf16x2 h2v = *(const bf16x2*)(h + (size_t)s2 * EMB + c0);
        bf16x2 h3 = *(const bf16x2*)(h + (size_t)s3 * EMB + c0);
        bf16x2 h4 = *(const bf16x2*)(h + (size_t)s4 * EMB + c0);
        bf16x2 h5 = *(const bf16x2*)(h + (size_t)s5 * EMB + c0);
        bf16x2 h6 = *(const bf16x2*)(h + (size_t)s6 * EMB + c0);
        bf16x2 h7 = *(const bf16x2*)(h + (size_t)s7 * EMB + c0);
        ax += (float)h0.x + (float)h1.x + (float)h2v.x + (float)h3.x
            + (float)h4.x + (float)h5.x + (float)h6.x + (float)h7.x;
        ay += (float)h0.y + (float)h1.y + (float)h2v.y + (float)h3.y
            + (float)h4.y + (float)h5.y + (float)h6.y + (float)h7.y;
    }
    for (; j < re; ++j) {
        int s = csr_src[j];
        bf16x2 hv = *(const bf16x2*)(h + (size_t)s * EMB + c0);
        ax += (float)hv.x; ay += (float)hv.y;
    }
    ax += (float)hself.x; ay += (float)hself.y;
    {   // + ea_agg[i] @ We[l]   (WeT fp32 layout: [c][16f] contiguous)
        const float* ea = ea_agg + node * EDGE_F;
        const float* w0 = weT_l + (size_t)c0 * 16;
        const float* w1 = weT_l + (size_t)(c0 + 1) * 16;
#pragma unroll
        for (int f = 0; f < 16; ++f) {
            float ef = ea[f];
            ax += ef * w0[f];
            ay += ef * w1[f];
        }
    }
    {   // + (deg+1) * be[l]
        float dp1 = (float)(re - rs + 1);
        ax += dp1 * be_l[c0];
        ay += dp1 * be_l[c0 + 1];
    }
    bf16x2 o; o.x = (bf16)ax; o.y = (bf16)ay;
    *(bf16x2*)(agg + (size_t)node * EMB + c0) = o;
}

// ---------------------------------------------------------------------------
// GEMM: C[M,N] = op(A[M,K] @ Bswz + bias). One wave computes a 16-row x N
// strip. A-fragments (bf16, or fp32 converted in-flight) and pre-swizzled
// bf16 B-fragments are direct 16B global loads (no LDS). Output bf16.
// STATS: per-column sum/sumsq -> shfl reduce -> LDS cross-wave reduce ->
// ONE 256-float partial per block written to global (NO contended atomics;
// round-2 profile showed 800K same-line atomicAdds cost 138us/launch).
// ---------------------------------------------------------------------------
template <int K, int N, bool RELU, bool AFP32, bool STATS>
__global__ __launch_bounds__(256) void gemm_kernel(
    const void* __restrict__ Ap, const bf16* __restrict__ Bswz,
    const float* __restrict__ bias, bf16* __restrict__ outp,
    float* __restrict__ psum, int M)
{
    __shared__ float lstat[STATS ? 1024 : 1];
    if constexpr (STATS) {
        for (int i = threadIdx.x; i < 1024; i += 256) lstat[i] = 0.f;
        __syncthreads();
    }
    const int lane = threadIdx.x & 63;
    const int wave = threadIdx.x >> 6;
    const int m0 = (blockIdx.x * 4 + wave) * 16;
    if (m0 >= M) return;
    const int m = lane & 15, q = lane >> 4;
    constexpr int NF = N / 16, KB = K / 32;

    f32x4 acc[NF];
#pragma unroll
    for (int f = 0; f < NF; ++f) acc[f] = 0.f;

#pragma unroll
    for (int kb = 0; kb < KB; ++kb) {
        bf16x8 a;
        if constexpr (AFP32) {
            const float* ar = (const float*)Ap + (size_t)(m0 + m) * K + kb * 32 + q * 8;
            f32x4 v0 = *(const f32x4*)ar;
            f32x4 v1 = *(const f32x4*)(ar + 4);
#pragma unroll
            for (int j = 0; j < 4; ++j) { a[j] = (bf16)v0[j]; a[4 + j] = (bf16)v1[j]; }
        } else {
            const bf16* ar = (const bf16*)Ap + (size_t)(m0 + m) * K + kb * 32 + q * 8;
            a = *(const bf16x8*)ar;
        }
#pragma unroll
        for (int f = 0; f < NF; ++f) {
            bf16x8 b = *(const bf16x8*)(Bswz + ((size_t)(kb * N + f * 16 + m)) * 32 + q * 8);
            acc[f] = __builtin_amdgcn_mfma_f32_16x16x32_bf16(a, b, acc[f], 0, 0, 0);
        }
    }

#pragma unroll
    for (int f = 0; f < NF; ++f) {
        const int col = f * 16 + m;
        float bv = bias[col];
        float s1 = 0.f, s2 = 0.f;
#pragma unroll
        for (int r = 0; r < 4; ++r) {
            float v = acc[f][r] + bv;
            if (RELU) v = fmaxf(v, 0.f);
            int row = m0 + q * 4 + r;
            outp[(size_t)row * N + col] = (bf16)v;
            if constexpr (STATS) { s1 += v; s2 += v * v; }
        }
        if constexpr (STATS) {
            s1 += __shfl_xor(s1, 16); s1 += __shfl_xor(s1, 32);
            s2 += __shfl_xor(s2, 16); s2 += __shfl_xor(s2, 32);
            if (q == 0) {
                lstat[wave * 128 + col] = s1;
                lstat[512 + wave * 128 + col] = s2;
            }
        }
    }
    if constexpr (STATS) {
        __syncthreads();
        int t = threadIdx.x;
        if (t < 128) {
            float s = lstat[t] + lstat[128 + t] + lstat[256 + t] + lstat[384 + t];
            float ssq = lstat[512 + t] + lstat[640 + t] + lstat[768 + t] + lstat[896 + t];
            psum[(size_t)blockIdx.x * 256 + t] = s;
            psum[(size_t)blockIdx.x * 256 + 128 + t] = ssq;
        }
    }
}

// ---------------------------------------------------------------------------
// Reduce per-block stats partials -> stats[256] (sums | sumsq).
// 8 blocks x 256 threads, 2K low-contention atomics total.
// ---------------------------------------------------------------------------
__global__ __launch_bounds__(256) void reduce_stats_kernel(
    const float* __restrict__ psum, float* __restrict__ stats, int nblk)
{
    int c = threadIdx.x;
    float acc = 0.f;
    for (int b = blockIdx.x; b < nblk; b += gridDim.x)
        acc += psum[(size_t)b * 256 + c];
    atomicAdd(&stats[c], acc);
}

// ---------------------------------------------------------------------------
// BatchNorm normalize (+optional relu), bf16 in -> bf16 (intermediate h) or
// fp32 (final d_out). scale/shift recomputed per block from stats.
// ---------------------------------------------------------------------------
__global__ __launch_bounds__(256) void norm_kernel(
    const bf16* __restrict__ h2, const float* __restrict__ sums,
    const float* __restrict__ sumsq, const float* __restrict__ gamma,
    const float* __restrict__ beta, void* __restrict__ outp, int n,
    int relu, int out_fp32)
{
    __shared__ float sc[EMB], sh[EMB];
    int tid = threadIdx.x;
    if (tid < EMB) {
        float inv_n = 1.0f / (float)n;
        float mean = sums[tid] * inv_n;
        float var = sumsq[tid] * inv_n - mean * mean;
        float s = gamma[tid] * rsqrtf(var + 1e-5f);
        sc[tid] = s;
        sh[tid] = beta[tid] - mean * s;
    }
    __syncthreads();
    int total4 = n * (EMB / 4);
    int stride = gridDim.x * blockDim.x;
    for (int i = blockIdx.x * blockDim.x + tid; i < total4; i += stride) {
        bf16x4 hv = ((const bf16x4*)h2)[i];
        int c0 = (i * 4) & (EMB - 1);
        float v0 = (float)hv.x * sc[c0] + sh[c0];
        float v1 = (float)hv.y * sc[c0 + 1] + sh[c0 + 1];
        float v2 = (float)hv.z * sc[c0 + 2] + sh[c0 + 2];
        float v3 = (float)hv.w * sc[c0 + 3] + sh[c0 + 3];
        if (relu) {
            v0 = fmaxf(v0, 0.f); v1 = fmaxf(v1, 0.f);
            v2 = fmaxf(v2, 0.f); v3 = fmaxf(v3, 0.f);
        }
        if (out_fp32) {
            f32x4 o; o.x = v0; o.y = v1; o.z = v2; o.w = v3;
            ((f32x4*)outp)[i] = o;
        } else {
            bf16x4 o;
            o.x = (bf16)v0; o.y = (bf16)v1; o.z = (bf16)v2; o.w = (bf16)v3;
            ((bf16x4*)outp)[i] = o;
        }
    }
}

// ---------------------------------------------------------------------------
extern "C" void kernel_launch(void* const* d_in, const int* in_sizes, int n_in,
                              void* d_out, int out_size, void* d_ws, size_t ws_size,
                              hipStream_t stream)
{
    const float* x         = (const float*)d_in[0];
    const float* edge_attr = (const float*)d_in[1];
    const int*   eidx      = (const int*)d_in[2];
    const float* Wx        = (const float*)d_in[3];
    const float* bx        = (const float*)d_in[4];
    const float* We        = (const float*)d_in[5];
    const float* be        = (const float*)d_in[6];
    const float* W1        = (const float*)d_in[7];
    const float* b1        = (const float*)d_in[8];
    const float* W2        = (const float*)d_in[9];
    const float* b2        = (const float*)d_in[10];
    const float* gamma     = (const float*)d_in[11];
    const float* beta      = (const float*)d_in[12];

    // ---- workspace layout (poisoned 0xAA before every call) ----
    size_t off = 0;
    char* base = (char*)d_ws;
    auto alloc = [&](size_t bytes) -> void* {
        void* p = base + off;
        off += (bytes + 255) & ~(size_t)255;
        return p;
    };
    int*   deg      = (int*)alloc(NN * 4);
    float* stats    = (float*)alloc(NLAYER * 256 * 4);   // per layer: 128 sums | 128 sumsq
    size_t zero_bytes = off;                             // deg + stats zeroed
    int*   rowstart = (int*)alloc((NN + 1) * 4);
    int*   cursor   = (int*)alloc(NN * 4);
    int*   bsum     = (int*)alloc(SCAN_BLOCKS * 4);
    int*   boff     = (int*)alloc(SCAN_BLOCKS * 4);
    int*   csr_src  = (int*)alloc((size_t)NE * 4);
    int*   csr_e    = (int*)alloc((size_t)NE * 4);
    float* ea_agg   = (float*)alloc((size_t)NN * EDGE_F * 4);
    bf16*  h        = (bf16*)alloc((size_t)NN * EMB * 2);
    bf16*  aggb     = (bf16*)alloc((size_t)NN * EMB * 2);
    bf16*  t1       = (bf16*)alloc((size_t)NN * 2 * EMB * 2);
    bf16*  h2b      = (bf16*)alloc((size_t)NN * EMB * 2);
    float* psum     = (float*)alloc((size_t)782 * 256 * 4);
    bf16*  wx_s     = (bf16*)alloc(16384 * 2);
    bf16*  w1_s     = (bf16*)alloc(163840 * 2);
    bf16*  w2_s     = (bf16*)alloc(163840 * 2);
    float* weT      = (float*)alloc(10240 * 4);
    (void)ws_size; (void)in_sizes; (void)n_in; (void)out_size;

    const int* src = eidx;
    const int* dst = eidx + NE;

    hipMemsetAsync(d_ws, 0, zero_bytes, stream);

    swz_kernel<<<1384, 256, 0, stream>>>(Wx, W1, W2, We, wx_s, w1_s, w2_s, weT);
    count_kernel<<<NE / 256, 256, 0, stream>>>(dst, deg, NE);
    deg_bsum_kernel<<<SCAN_BLOCKS, 256, 0, stream>>>(deg, bsum, NN);
    bsum_scan_kernel<<<1, 256, 0, stream>>>(bsum, boff, rowstart, SCAN_BLOCKS, NN);
    chunk_scan_kernel<<<SCAN_BLOCKS, 256, 0, stream>>>(deg, boff, rowstart, cursor, NN);
    fill_kernel<<<NE / 256, 256, 0, stream>>>(src, dst, cursor, csr_src, csr_e, NE);
    ea_gather_kernel<<<NN / 16, 256, 0, stream>>>(edge_attr, rowstart, csr_e, ea_agg, NN);

    // h = x @ Wx + bx  (x is fp32, converted in-kernel)
    const int gemm_blocks = (NN / 16 + 3) / 4;   // 782
    gemm_kernel<128, 128, false, true, false><<<gemm_blocks, 256, 0, stream>>>(
        x, wx_s, bx, h, nullptr, NN);

    for (int l = 0; l < NLAYER; ++l) {
        float* stats_l = stats + l * 256;
        agg_kernel<<<NN / 4, 256, 0, stream>>>(
            h, rowstart, csr_src, ea_agg, weT + l * 2048, be + l * EMB, aggb, NN);
        gemm_kernel<128, 256, true, false, false><<<gemm_blocks, 256, 0, stream>>>(
            aggb, w1_s + l * 32768, b1 + l * 2 * EMB, t1, nullptr, NN);
        gemm_kernel<256, 128, false, false, true><<<gemm_blocks, 256, 0, stream>>>(
            t1, w2_s + l * 32768, b2 + l * EMB, h2b, psum, NN);
        reduce_stats_kernel<<<8, 256, 0, stream>>>(psum, stats_l, gemm_blocks);
        norm_kernel<<<1024, 256, 0, stream>>>(
            h2b, stats_l, stats_l + 128, gamma + l * EMB, beta + l * EMB,
            (l == NLAYER - 1) ? d_out : (void*)h, NN,
            (l < NLAYER - 1) ? 1 : 0, (l == NLAYER - 1) ? 1 : 0);
    }
}

// Round 4
// 1029.448 us; speedup vs baseline: 1.4526x; 1.0008x over previous
//
#include <hip/hip_runtime.h>

typedef __bf16 bf16;
typedef __bf16 bf16x2 __attribute__((ext_vector_type(2)));
typedef __bf16 bf16x4 __attribute__((ext_vector_type(4)));
typedef __bf16 bf16x8 __attribute__((ext_vector_type(8)));
typedef float f32x4 __attribute__((ext_vector_type(4)));

#define NN 50000
#define NE 800000
#define EMB 128
#define EDGE_F 16
#define NLAYER 5
#define SCAN_BLOCKS 196   // ceil(50000/256)

// ---------------------------------------------------------------------------
// Weight swizzle + fp32->bf16 convert: row-major [K][N] -> [(k/32)][n][k%32]
// so an MFMA B-fragment (n = lane&15, k = (lane>>4)*8 + j) is one contiguous
// 16B load per lane. Also builds WeT[l][c][f] = We[l][f][c] (kept fp32).
// ---------------------------------------------------------------------------
__global__ __launch_bounds__(256) void swz_kernel(
    const float* __restrict__ Wx, const float* __restrict__ W1,
    const float* __restrict__ W2, const float* __restrict__ We,
    bf16* __restrict__ wx_s, bf16* __restrict__ w1_s,
    bf16* __restrict__ w2_s, float* __restrict__ weT)
{
    int t = blockIdx.x * 256 + threadIdx.x;
    if (t < 16384) {                                   // Wx: K=128,N=128
        int k = t >> 7, n = t & 127;
        wx_s[(((k >> 5) << 7) + n) * 32 + (k & 31)] = (bf16)Wx[t];
    } else if (t < 16384 + 163840) {                   // W1: 5 x (K=128,N=256)
        int u = t - 16384;
        int l = u / 32768, r = u % 32768;
        int k = r >> 8, n = r & 255;
        w1_s[l * 32768 + (((k >> 5) << 8) + n) * 32 + (k & 31)] = (bf16)W1[u];
    } else if (t < 16384 + 327680) {                   // W2: 5 x (K=256,N=128)
        int u = t - (16384 + 163840);
        int l = u / 32768, r = u % 32768;
        int k = r >> 7, n = r & 127;
        w2_s[l * 32768 + (((k >> 5) << 7) + n) * 32 + (k & 31)] = (bf16)W2[u];
    } else if (t < 16384 + 327680 + 10240) {           // WeT: 5 x [128][16] fp32
        int u = t - (16384 + 327680);
        int l = u >> 11, r = u & 2047;
        int c = r >> 4, f = r & 15;
        weT[u] = We[l * 2048 + f * 128 + c];
    }
}

// ---------------------------------------------------------------------------
// CSR build: count -> hierarchical scan (3 small kernels) -> fill
// ---------------------------------------------------------------------------
__global__ void count_kernel(const int* __restrict__ dst, int* __restrict__ deg, int nE)
{
    int e = blockIdx.x * 256 + threadIdx.x;
    if (e < nE) atomicAdd(&deg[dst[e]], 1);
}

__global__ __launch_bounds__(256) void deg_bsum_kernel(
    const int* __restrict__ deg, int* __restrict__ bsum, int n)
{
    __shared__ int red[256];
    int i = blockIdx.x * 256 + threadIdx.x;
    red[threadIdx.x] = (i < n) ? deg[i] : 0;
    __syncthreads();
    for (int s = 128; s > 0; s >>= 1) {
        if (threadIdx.x < s) red[threadIdx.x] += red[threadIdx.x + s];
        __syncthreads();
    }
    if (threadIdx.x == 0) bsum[blockIdx.x] = red[0];
}

__global__ __launch_bounds__(256) void bsum_scan_kernel(
    const int* __restrict__ bsum, int* __restrict__ boff,
    int* __restrict__ rowstart, int nb, int n)
{
    __shared__ int v[256];
    int t = threadIdx.x;
    v[t] = (t < nb) ? bsum[t] : 0;
    __syncthreads();
    if (t == 0) {
        int r = 0;
        for (int i = 0; i < nb; ++i) { int x = v[i]; v[i] = r; r += x; }
        rowstart[n] = r;
    }
    __syncthreads();
    if (t < nb) boff[t] = v[t];
}

__global__ __launch_bounds__(256) void chunk_scan_kernel(
    const int* __restrict__ deg, const int* __restrict__ boff,
    int* __restrict__ rowstart, int* __restrict__ cursor, int n)
{
    __shared__ int v[256];
    int t = threadIdx.x;
    int i = blockIdx.x * 256 + t;
    int x = (i < n) ? deg[i] : 0;
    v[t] = x;
    __syncthreads();
    // Hillis-Steele inclusive scan
    for (int s = 1; s < 256; s <<= 1) {
        int add = (t >= s) ? v[t - s] : 0;
        __syncthreads();
        v[t] += add;
        __syncthreads();
    }
    int ex = v[t] - x + boff[blockIdx.x];
    if (i < n) { rowstart[i] = ex; cursor[i] = ex; }
}

__global__ void fill_kernel(const int* __restrict__ src, const int* __restrict__ dst,
                            int* __restrict__ cursor, int* __restrict__ csr_src,
                            int* __restrict__ csr_e, int nE)
{
    int e = blockIdx.x * 256 + threadIdx.x;
    if (e < nE) {
        int d = dst[e];
        int pos = atomicAdd(&cursor[d], 1);
        csr_src[pos] = src[e];
        csr_e[pos] = e;
    }
}

// ---------------------------------------------------------------------------
// ea_agg[i][f] = sum over in-edges e of edge_attr[e][f]  (layer-independent)
// 16 lanes per node. edge_attr is fp32.
// ---------------------------------------------------------------------------
__global__ __launch_bounds__(256) void ea_gather_kernel(
    const float* __restrict__ edge_attr, const int* __restrict__ rowstart,
    const int* __restrict__ csr_e, float* __restrict__ ea_agg, int n)
{
    int node = blockIdx.x * 16 + (threadIdx.x >> 4);
    int f = threadIdx.x & 15;
    if (node >= n) return;
    int rs = rowstart[node], re = rowstart[node + 1];
    float a = 0.f;
    for (int j = rs; j < re; ++j) {
        int e = csr_e[j];
        a += edge_attr[(size_t)e * EDGE_F + f];
    }
    ea_agg[node * EDGE_F + f] = a;
}

// ---------------------------------------------------------------------------
// agg[i] = sum_{e:dst=i} h[src_e] + h[i] + ea_agg[i]@We[l] + (deg+1)*be[l]
// QUARTER-WAVE per node: 16 lanes x 16B (bf16x8) cover one 256B h-row, so one
// wave-level vmem instruction gathers 4 different rows (round-3 profile:
// latency-bound at 58 cyc/gather-instr with only 1 row/instr). Unroll 8 ->
// up to 32 edges in flight per wave. fp32 accumulate, bf16 out.
// ---------------------------------------------------------------------------
__global__ __launch_bounds__(256) void agg_kernel(
    const bf16* __restrict__ h, const int* __restrict__ rowstart,
    const int* __restrict__ csr_src, const float* __restrict__ ea_agg,
    const float* __restrict__ weT_l, const float* __restrict__ be_l,
    bf16* __restrict__ agg, int n)
{
    const int tid = threadIdx.x;
    const int qlane = tid & 15;                 // lane within quarter-wave
    const int node = blockIdx.x * 16 + (tid >> 4);
    if (node >= n) return;                      // 3125*16 == 50000 exactly
    const int c0 = qlane * 8;                   // 8 channels per lane
    const int rs = rowstart[node], re = rowstart[node + 1];

    float acc[8];
#pragma unroll
    for (int k = 0; k < 8; ++k) acc[k] = 0.f;

    const bf16* hq = h + c0;
    bf16x8 hself = *(const bf16x8*)(hq + (size_t)node * EMB);

    int j = rs;
    for (; j + 8 <= re; j += 8) {
        int s0 = csr_src[j],     s1 = csr_src[j + 1], s2 = csr_src[j + 2], s3 = csr_src[j + 3];
        int s4 = csr_src[j + 4], s5 = csr_src[j + 5], s6 = csr_src[j + 6], s7 = csr_src[j + 7];
        bf16x8 r0 = *(const bf16x8*)(hq + (size_t)s0 * EMB);
        bf16x8 r1 = *(const bf16x8*)(hq + (size_t)s1 * EMB);
        bf16x8 r2 = *(const bf16x8*)(hq + (size_t)s2 * EMB);
        bf16x8 r3 = *(const bf16x8*)(hq + (size_t)s3 * EMB);
        bf16x8 r4 = *(const bf16x8*)(hq + (size_t)s4 * EMB);
        bf16x8 r5 = *(const bf16x8*)(hq + (size_t)s5 * EMB);
        bf16x8 r6 = *(const bf16x8*)(hq + (size_t)s6 * EMB);
        bf16x8 r7 = *(const bf16x8*)(hq + (size_t)s7 * EMB);
#pragma unroll
        for (int k = 0; k < 8; ++k) {
            acc[k] += ((float)r0[k] + (float)r1[k]) + ((float)r2[k] + (float)r3[k])
                    + ((float)r4[k] + (float)r5[k]) + ((float)r6[k] + (float)r7[k]);
        }
    }
    for (; j < re; ++j) {
        int s = csr_src[j];
        bf16x8 r = *(const bf16x8*)(hq + (size_t)s * EMB);
#pragma unroll
        for (int k = 0; k < 8; ++k) acc[k] += (float)r[k];
    }
#pragma unroll
    for (int k = 0; k < 8; ++k) acc[k] += (float)hself[k];

    // + ea_agg[node] @ We[l]  (weT fp32 [c][16f]) and + (deg+1)*be[l]
    const float* ea = ea_agg + (size_t)node * EDGE_F;
    f32x4 e0 = *(const f32x4*)ea;
    f32x4 e1 = *(const f32x4*)(ea + 4);
    f32x4 e2 = *(const f32x4*)(ea + 8);
    f32x4 e3 = *(const f32x4*)(ea + 12);
    float dp1 = (float)(re - rs + 1);
    bf16x8 o;
#pragma unroll
    for (int k = 0; k < 8; ++k) {
        const float* w = weT_l + (size_t)(c0 + k) * EDGE_F;
        f32x4 w0 = *(const f32x4*)w;
        f32x4 w1 = *(const f32x4*)(w + 4);
        f32x4 w2 = *(const f32x4*)(w + 8);
        f32x4 w3 = *(const f32x4*)(w + 12);
        float d = e0.x * w0.x + e0.y * w0.y + e0.z * w0.z + e0.w * w0.w
                + e1.x * w1.x + e1.y * w1.y + e1.z * w1.z + e1.w * w1.w
                + e2.x * w2.x + e2.y * w2.y + e2.z * w2.z + e2.w * w2.w
                + e3.x * w3.x + e3.y * w3.y + e3.z * w3.z + e3.w * w3.w;
        o[k] = (bf16)(acc[k] + d + dp1 * be_l[c0 + k]);
    }
    *(bf16x8*)(agg + (size_t)node * EMB + c0) = o;
}

// ---------------------------------------------------------------------------
// GEMM: C[M,N] = op(A[M,K] @ Bswz + bias). One wave computes a 16-row x N
// strip. A-fragments (bf16, or fp32 converted in-flight) and pre-swizzled
// bf16 B-fragments are direct 16B global loads (no LDS). Output bf16.
// STATS: per-column sum/sumsq -> shfl reduce -> LDS cross-wave reduce ->
// ONE 256-float partial per block written to global (no contended atomics).
// ---------------------------------------------------------------------------
template <int K, int N, bool RELU, bool AFP32, bool STATS>
__global__ __launch_bounds__(256) void gemm_kernel(
    const void* __restrict__ Ap, const bf16* __restrict__ Bswz,
    const float* __restrict__ bias, bf16* __restrict__ outp,
    float* __restrict__ psum, int M)
{
    __shared__ float lstat[STATS ? 1024 : 1];
    if constexpr (STATS) {
        for (int i = threadIdx.x; i < 1024; i += 256) lstat[i] = 0.f;
        __syncthreads();
    }
    const int lane = threadIdx.x & 63;
    const int wave = threadIdx.x >> 6;
    const int m0 = (blockIdx.x * 4 + wave) * 16;
    if (m0 >= M) return;
    const int m = lane & 15, q = lane >> 4;
    constexpr int NF = N / 16, KB = K / 32;

    f32x4 acc[NF];
#pragma unroll
    for (int f = 0; f < NF; ++f) acc[f] = 0.f;

#pragma unroll
    for (int kb = 0; kb < KB; ++kb) {
        bf16x8 a;
        if constexpr (AFP32) {
            const float* ar = (const float*)Ap + (size_t)(m0 + m) * K + kb * 32 + q * 8;
            f32x4 v0 = *(const f32x4*)ar;
            f32x4 v1 = *(const f32x4*)(ar + 4);
#pragma unroll
            for (int j = 0; j < 4; ++j) { a[j] = (bf16)v0[j]; a[4 + j] = (bf16)v1[j]; }
        } else {
            const bf16* ar = (const bf16*)Ap + (size_t)(m0 + m) * K + kb * 32 + q * 8;
            a = *(const bf16x8*)ar;
        }
#pragma unroll
        for (int f = 0; f < NF; ++f) {
            bf16x8 b = *(const bf16x8*)(Bswz + ((size_t)(kb * N + f * 16 + m)) * 32 + q * 8);
            acc[f] = __builtin_amdgcn_mfma_f32_16x16x32_bf16(a, b, acc[f], 0, 0, 0);
        }
    }

#pragma unroll
    for (int f = 0; f < NF; ++f) {
        const int col = f * 16 + m;
        float bv = bias[col];
        float s1 = 0.f, s2 = 0.f;
#pragma unroll
        for (int r = 0; r < 4; ++r) {
            float v = acc[f][r] + bv;
            if (RELU) v = fmaxf(v, 0.f);
            int row = m0 + q * 4 + r;
            outp[(size_t)row * N + col] = (bf16)v;
            if constexpr (STATS) { s1 += v; s2 += v * v; }
        }
        if constexpr (STATS) {
            s1 += __shfl_xor(s1, 16); s1 += __shfl_xor(s1, 32);
            s2 += __shfl_xor(s2, 16); s2 += __shfl_xor(s2, 32);
            if (q == 0) {
                lstat[wave * 128 + col] = s1;
                lstat[512 + wave * 128 + col] = s2;
            }
        }
    }
    if constexpr (STATS) {
        __syncthreads();
        int t = threadIdx.x;
        if (t < 128) {
            float s = lstat[t] + lstat[128 + t] + lstat[256 + t] + lstat[384 + t];
            float ssq = lstat[512 + t] + lstat[640 + t] + lstat[768 + t] + lstat[896 + t];
            psum[(size_t)blockIdx.x * 256 + t] = s;
            psum[(size_t)blockIdx.x * 256 + 128 + t] = ssq;
        }
    }
}

// ---------------------------------------------------------------------------
// Reduce per-block stats partials -> stats[256] (sums | sumsq).
// ---------------------------------------------------------------------------
__global__ __launch_bounds__(256) void reduce_stats_kernel(
    const float* __restrict__ psum, float* __restrict__ stats, int nblk)
{
    int c = threadIdx.x;
    float acc = 0.f;
    for (int b = blockIdx.x; b < nblk; b += gridDim.x)
        acc += psum[(size_t)b * 256 + c];
    atomicAdd(&stats[c], acc);
}

// ---------------------------------------------------------------------------
// BatchNorm normalize (+optional relu), bf16 in -> bf16 (intermediate h) or
// fp32 (final d_out). scale/shift recomputed per block from stats.
// ---------------------------------------------------------------------------
__global__ __launch_bounds__(256) void norm_kernel(
    const bf16* __restrict__ h2, const float* __restrict__ sums,
    const float* __restrict__ sumsq, const float* __restrict__ gamma,
    const float* __restrict__ beta, void* __restrict__ outp, int n,
    int relu, int out_fp32)
{
    __shared__ float sc[EMB], sh[EMB];
    int tid = threadIdx.x;
    if (tid < EMB) {
        float inv_n = 1.0f / (float)n;
        float mean = sums[tid] * inv_n;
        float var = sumsq[tid] * inv_n - mean * mean;
        float s = gamma[tid] * rsqrtf(var + 1e-5f);
        sc[tid] = s;
        sh[tid] = beta[tid] - mean * s;
    }
    __syncthreads();
    int total4 = n * (EMB / 4);
    int stride = gridDim.x * blockDim.x;
    for (int i = blockIdx.x * blockDim.x + tid; i < total4; i += stride) {
        bf16x4 hv = ((const bf16x4*)h2)[i];
        int c0 = (i * 4) & (EMB - 1);
        float v0 = (float)hv.x * sc[c0] + sh[c0];
        float v1 = (float)hv.y * sc[c0 + 1] + sh[c0 + 1];
        float v2 = (float)hv.z * sc[c0 + 2] + sh[c0 + 2];
        float v3 = (float)hv.w * sc[c0 + 3] + sh[c0 + 3];
        if (relu) {
            v0 = fmaxf(v0, 0.f); v1 = fmaxf(v1, 0.f);
            v2 = fmaxf(v2, 0.f); v3 = fmaxf(v3, 0.f);
        }
        if (out_fp32) {
            f32x4 o; o.x = v0; o.y = v1; o.z = v2; o.w = v3;
            ((f32x4*)outp)[i] = o;
        } else {
            bf16x4 o;
            o.x = (bf16)v0; o.y = (bf16)v1; o.z = (bf16)v2; o.w = (bf16)v3;
            ((bf16x4*)outp)[i] = o;
        }
    }
}

// ---------------------------------------------------------------------------
extern "C" void kernel_launch(void* const* d_in, const int* in_sizes, int n_in,
                              void* d_out, int out_size, void* d_ws, size_t ws_size,
                              hipStream_t stream)
{
    const float* x         = (const float*)d_in[0];
    const float* edge_attr = (const float*)d_in[1];
    const int*   eidx      = (const int*)d_in[2];
    const float* Wx        = (const float*)d_in[3];
    const float* bx        = (const float*)d_in[4];
    const float* We        = (const float*)d_in[5];
    const float* be        = (const float*)d_in[6];
    const float* W1        = (const float*)d_in[7];
    const float* b1        = (const float*)d_in[8];
    const float* W2        = (const float*)d_in[9];
    const float* b2        = (const float*)d_in[10];
    const float* gamma     = (const float*)d_in[11];
    const float* beta      = (const float*)d_in[12];

    // ---- workspace layout (poisoned 0xAA before every call) ----
    size_t off = 0;
    char* base = (char*)d_ws;
    auto alloc = [&](size_t bytes) -> void* {
        void* p = base + off;
        off += (bytes + 255) & ~(size_t)255;
        return p;
    };
    int*   deg      = (int*)alloc(NN * 4);
    float* stats    = (float*)alloc(NLAYER * 256 * 4);   // per layer: 128 sums | 128 sumsq
    size_t zero_bytes = off;                             // deg + stats zeroed
    int*   rowstart = (int*)alloc((NN + 1) * 4);
    int*   cursor   = (int*)alloc(NN * 4);
    int*   bsum     = (int*)alloc(SCAN_BLOCKS * 4);
    int*   boff     = (int*)alloc(SCAN_BLOCKS * 4);
    int*   csr_src  = (int*)alloc((size_t)NE * 4);
    int*   csr_e    = (int*)alloc((size_t)NE * 4);
    float* ea_agg   = (float*)alloc((size_t)NN * EDGE_F * 4);
    bf16*  h        = (bf16*)alloc((size_t)NN * EMB * 2);
    bf16*  aggb     = (bf16*)alloc((size_t)NN * EMB * 2);
    bf16*  t1       = (bf16*)alloc((size_t)NN * 2 * EMB * 2);
    bf16*  h2b      = (bf16*)alloc((size_t)NN * EMB * 2);
    float* psum     = (float*)alloc((size_t)782 * 256 * 4);
    bf16*  wx_s     = (bf16*)alloc(16384 * 2);
    bf16*  w1_s     = (bf16*)alloc(163840 * 2);
    bf16*  w2_s     = (bf16*)alloc(163840 * 2);
    float* weT      = (float*)alloc(10240 * 4);
    (void)ws_size; (void)in_sizes; (void)n_in; (void)out_size;

    const int* src = eidx;
    const int* dst = eidx + NE;

    hipMemsetAsync(d_ws, 0, zero_bytes, stream);

    swz_kernel<<<1384, 256, 0, stream>>>(Wx, W1, W2, We, wx_s, w1_s, w2_s, weT);
    count_kernel<<<NE / 256, 256, 0, stream>>>(dst, deg, NE);
    deg_bsum_kernel<<<SCAN_BLOCKS, 256, 0, stream>>>(deg, bsum, NN);
    bsum_scan_kernel<<<1, 256, 0, stream>>>(bsum, boff, rowstart, SCAN_BLOCKS, NN);
    chunk_scan_kernel<<<SCAN_BLOCKS, 256, 0, stream>>>(deg, boff, rowstart, cursor, NN);
    fill_kernel<<<NE / 256, 256, 0, stream>>>(src, dst, cursor, csr_src, csr_e, NE);
    ea_gather_kernel<<<NN / 16, 256, 0, stream>>>(edge_attr, rowstart, csr_e, ea_agg, NN);

    // h = x @ Wx + bx  (x is fp32, converted in-kernel)
    const int gemm_blocks = (NN / 16 + 3) / 4;   // 782
    gemm_kernel<128, 128, false, true, false><<<gemm_blocks, 256, 0, stream>>>(
        x, wx_s, bx, h, nullptr, NN);

    for (int l = 0; l < NLAYER; ++l) {
        float* stats_l = stats + l * 256;
        agg_kernel<<<NN / 16, 256, 0, stream>>>(
            h, rowstart, csr_src, ea_agg, weT + l * 2048, be + l * EMB, aggb, NN);
        gemm_kernel<128, 256, true, false, false><<<gemm_blocks, 256, 0, stream>>>(
            aggb, w1_s + l * 32768, b1 + l * 2 * EMB, t1, nullptr, NN);
        gemm_kernel<256, 128, false, false, true><<<gemm_blocks, 256, 0, stream>>>(
            t1, w2_s + l * 32768, b2 + l * EMB, h2b, psum, NN);
        reduce_stats_kernel<<<8, 256, 0, stream>>>(psum, stats_l, gemm_blocks);
        norm_kernel<<<1024, 256, 0, stream>>>(
            h2b, stats_l, stats_l + 128, gamma + l * EMB, beta + l * EMB,
            (l == NLAYER - 1) ? d_out : (void*)h, NN,
            (l < NLAYER - 1) ? 1 : 0, (l == NLAYER - 1) ? 1 : 0);
    }
}